// Round 1
// baseline (427.454 us; speedup 1.0000x reference)
//
#include <hip/hip_runtime.h>

// LSTM_13451837571407: B=1048576, I=14, H=16, L=8, seq_len=1.
// Key simplifications:
//   layer 0: h=c=0  -> gates = x@W_ih0^T + (b_ih0 + b_hh0)
//   layer l>=1: input == hidden == h -> gates = h@(W_ih[l-1]+W_hh[l])^T + (b_ih[l]+b_hh[l])
// All weights combined into sW[8][64][16] (layer0 K padded 14->16 with zeros),
// staged in LDS (uniform broadcast reads). One thread per batch element, pure
// fp32 VALU (no fp32 MFMA on CDNA4).

__device__ __forceinline__ float fsig(float xv) {
    // 1/(1+e^-x); v_exp + v_rcp, saturates correctly.
    return __builtin_amdgcn_rcpf(1.0f + __expf(-xv));
}
__device__ __forceinline__ float ftanh(float xv) {
    // 1 - 2/(e^{2x}+1); e=inf -> 1, e=0 -> -1.
    float e = __expf(2.0f * xv);
    return 1.0f - 2.0f * __builtin_amdgcn_rcpf(e + 1.0f);
}

__global__ __launch_bounds__(256, 4) void lstm_fused_kernel(
    const float* __restrict__ x,      // [B][14]
    const float* __restrict__ W_ih0,  // [64][14]
    const float* __restrict__ W_ih,   // [7][64][16]
    const float* __restrict__ W_hh,   // [8][64][16]
    const float* __restrict__ b_ih,   // [8][64]
    const float* __restrict__ b_hh,   // [8][64]
    const float* __restrict__ fc_w,   // [16]
    const float* __restrict__ fc_b,   // [1]
    float* __restrict__ out,          // [B]
    int n)
{
    __shared__ __align__(16) float sW[8 * 64 * 16];  // 32 KB combined weights
    __shared__ float sbc[8 * 64];                    // combined biases
    __shared__ float sfc[17];                        // fc_w[16], fc_b

    const int tid = threadIdx.x;

    // ---- stage combined weights into LDS (weights are tiny; L2-resident) ----
    for (int idx = tid; idx < 1024; idx += 256) {     // layer 0, pad K 14->16
        int u = idx >> 4, k = idx & 15;
        sW[idx] = (k < 14) ? W_ih0[u * 14 + k] : 0.0f;
    }
    for (int idx = tid; idx < 7168; idx += 256) {     // layers 1..7 combined
        sW[1024 + idx] = W_ih[idx] + W_hh[1024 + idx];
    }
    for (int idx = tid; idx < 512; idx += 256) {      // combined biases
        sbc[idx] = b_ih[idx] + b_hh[idx];
    }
    if (tid < 16) sfc[tid] = fc_w[tid];
    if (tid == 16) sfc[16] = fc_b[0];
    __syncthreads();

    const int b = blockIdx.x * 256 + tid;
    if (b >= n) return;

    // ---- load x (padded to 16) ----
    float in[16];
    #pragma unroll
    for (int k = 0; k < 14; ++k) in[k] = x[b * 14 + k];
    in[14] = 0.0f; in[15] = 0.0f;

    float c[16];
    #pragma unroll
    for (int u = 0; u < 16; ++u) c[u] = 0.0f;

    // ---- 8 fused LSTM cell layers ----
    for (int l = 0; l < 8; ++l) {
        const float* W  = sW  + l * 1024;
        const float* bc = sbc + l * 64;
        float hn[16];
        #pragma unroll
        for (int u = 0; u < 16; ++u) {
            float gi = bc[u], gf = bc[16 + u], gg = bc[32 + u], go = bc[48 + u];
            const float4* Wi = (const float4*)(W + u * 16);
            const float4* Wf = (const float4*)(W + (16 + u) * 16);
            const float4* Wg = (const float4*)(W + (32 + u) * 16);
            const float4* Wo = (const float4*)(W + (48 + u) * 16);
            #pragma unroll
            for (int kq = 0; kq < 4; ++kq) {
                const float i0 = in[kq * 4 + 0], i1 = in[kq * 4 + 1];
                const float i2 = in[kq * 4 + 2], i3 = in[kq * 4 + 3];
                float4 wi = Wi[kq], wf = Wf[kq], wg = Wg[kq], wo = Wo[kq];
                gi += i0 * wi.x + i1 * wi.y + i2 * wi.z + i3 * wi.w;
                gf += i0 * wf.x + i1 * wf.y + i2 * wf.z + i3 * wf.w;
                gg += i0 * wg.x + i1 * wg.y + i2 * wg.z + i3 * wg.w;
                go += i0 * wo.x + i1 * wo.y + i2 * wo.z + i3 * wo.w;
            }
            float cn = fsig(gf) * c[u] + fsig(gi) * ftanh(gg);
            c[u] = cn;
            hn[u] = fsig(go) * ftanh(cn);
        }
        #pragma unroll
        for (int u = 0; u < 16; ++u) in[u] = hn[u];
    }

    // ---- FC head ----
    float acc = sfc[16];
    #pragma unroll
    for (int u = 0; u < 16; ++u) acc += in[u] * sfc[u];
    out[b] = acc;
}

extern "C" void kernel_launch(void* const* d_in, const int* in_sizes, int n_in,
                              void* d_out, int out_size, void* d_ws, size_t ws_size,
                              hipStream_t stream) {
    const float* x     = (const float*)d_in[0];
    const float* W_ih0 = (const float*)d_in[1];
    const float* W_ih  = (const float*)d_in[2];
    const float* W_hh  = (const float*)d_in[3];
    const float* b_ih  = (const float*)d_in[4];
    const float* b_hh  = (const float*)d_in[5];
    const float* fc_w  = (const float*)d_in[6];
    const float* fc_b  = (const float*)d_in[7];
    float* out = (float*)d_out;

    const int B = in_sizes[0] / 14;
    const int grid = (B + 255) / 256;
    lstm_fused_kernel<<<grid, 256, 0, stream>>>(
        x, W_ih0, W_ih, W_hh, b_ih, b_hh, fc_w, fc_b, out, B);
}

// Round 2
// 153.837 us; speedup vs baseline: 2.7786x; 2.7786x over previous
//
#include <hip/hip_runtime.h>

// LSTM_13451837571407 — MFMA bf16-split version.
// gates(layer l) = Wc[l][64x16] @ h^T[16 x 16batch] + bc[l]  (per 16-batch tile)
//   Wc[0] = W_ih0 (K padded 14->16), Wc[l>=1] = W_ih[l-1]+W_hh[l]  (h==input quirk)
// Folding: rows i,f,o scaled by -log2(e)  -> sigmoid(x) = 1/(1+exp2(y))
//          rows g     scaled by 2*log2(e) -> tanh(g)   = (exp2(y)-1)/(exp2(y)+1)
// Split: W = Whi + Wlo, h = hhi + hlo (bf16 truncation split); 3 MFMA products
// (hh*hh, hh*hl, hl*hh), fp32 accumulate -> ~fp32 accuracy.
// v_mfma_f32_16x16x16_bf16 layout (classic CDNA K16):
//   A: row=lane&15, k=4*(lane>>4)+j ; B: k=4*(lane>>4)+j, col=lane&15
//   D: col=lane&15 (batch), row=4*(lane>>4)+reg (unit within gate quadrant)
// => lane (b=lane&15, hi=lane>>4) computes h for units 4hi..4hi+3, which IS the
//    next layer's B-fragment for that lane. No cross-lane shuffles per layer.

typedef short bf16x4 __attribute__((ext_vector_type(4)));
typedef float f32x4 __attribute__((ext_vector_type(4)));

#if __has_builtin(__builtin_amdgcn_mfma_f32_16x16x16bf16_1k)
__device__ __forceinline__ f32x4 mfma16(bf16x4 a, bf16x4 b, f32x4 c) {
    return __builtin_amdgcn_mfma_f32_16x16x16bf16_1k(a, b, c, 0, 0, 0);
}
#else
__device__ __forceinline__ f32x4 mfma16(bf16x4 a, bf16x4 b, f32x4 c) {
    // fallback: raw instruction; conservative nops for MFMA->VALU hazard
    asm volatile("v_mfma_f32_16x16x16_bf16 %0, %1, %2, %0\n\ts_nop 7\n\ts_nop 7"
                 : "+v"(c) : "v"(a), "v"(b));
    return c;
}
#endif

#define NLOG2E  (-1.4426950408889634f)
#define G2LOG2E (2.8853900817779268f)
#define THREADS 512
#define WAVES_PB (THREADS / 64)
#define NBLOCKS 1024

__device__ __forceinline__ short tb(float v) {
    return (short)(__float_as_uint(v) >> 16);  // truncate-to-bf16
}

__global__ __launch_bounds__(THREADS, 4) void lstm_mfma_kernel(
    const float* __restrict__ x,      // [B][14]
    const float* __restrict__ W_ih0,  // [64][14]
    const float* __restrict__ W_ih,   // [7][64][16]
    const float* __restrict__ W_hh,   // [8][64][16]
    const float* __restrict__ b_ih,   // [8][64]
    const float* __restrict__ b_hh,   // [8][64]
    const float* __restrict__ fc_w,   // [16]
    const float* __restrict__ fc_b,   // [1]
    float* __restrict__ out,          // [B]
    int nB)
{
    __shared__ __align__(16) short sWh[8 * 64 * 16];  // folded weight hi (bf16)
    __shared__ __align__(16) short sWl[8 * 64 * 16];  // folded weight lo (bf16)
    __shared__ __align__(16) float sB[8 * 64];        // folded combined bias
    __shared__ __align__(16) float sFC[20];

    const int tid = threadIdx.x;

    // ---- per-block weight prep: combine, fold log2e, bf16-split ----
    for (int idx = tid; idx < 8192; idx += THREADS) {
        const int l = idx >> 10, rk = idx & 1023;
        const int row = rk >> 4, k = rk & 15;
        float w;
        if (l == 0) w = (k < 14) ? W_ih0[row * 14 + k] : 0.0f;
        else        w = W_ih[(l - 1) * 1024 + rk] + W_hh[l * 1024 + rk];
        const float scale = ((row >> 4) == 2) ? G2LOG2E : NLOG2E;
        w *= scale;
        const unsigned u = __float_as_uint(w);
        sWh[idx] = (short)(u >> 16);
        const float lo = w - __uint_as_float(u & 0xFFFF0000u);
        sWl[idx] = (short)(__float_as_uint(lo) >> 16);
    }
    for (int idx = tid; idx < 512; idx += THREADS) {
        const int row = idx & 63;
        const float scale = ((row >> 4) == 2) ? G2LOG2E : NLOG2E;
        sB[idx] = (b_ih[idx] + b_hh[idx]) * scale;
    }
    if (tid < 16) sFC[tid] = fc_w[tid];
    if (tid == 16) sFC[16] = fc_b[0];
    __syncthreads();

    const int lane = tid & 63;
    const int wv = tid >> 6;
    const int bcol = lane & 15;   // batch within tile (B-frag col / A-frag row)
    const int hi = lane >> 4;     // quad index (k-group / D-row group)

    const int n_tiles = (nB + 15) >> 4;
    const int waves_total = NBLOCKS * WAVES_PB;
    const int iters = (n_tiles + waves_total - 1) / waves_total;
    const int gw = blockIdx.x * WAVES_PB + wv;

    for (int it = 0; it < iters; ++it) {
        const int tile = gw * iters + it;
        if (tile >= n_tiles) break;
        const int batch = tile * 16 + bcol;
        const int bclamp = batch < nB ? batch : nB - 1;

        // ---- load x fragment: lane holds x[b][4hi .. 4hi+3] (pad 14->16) ----
        float v0 = 0.f, v1 = 0.f, v2 = 0.f, v3 = 0.f;
        {
            const float* xr = x + bclamp * 14 + hi * 4;
            const float2 p = *(const float2*)xr;
            v0 = p.x; v1 = p.y;
            if (hi < 3) {
                const float2 q = *(const float2*)(xr + 2);
                v2 = q.x; v3 = q.y;
            }
        }
        float hv[4] = {v0, v1, v2, v3};

        // bf16 split of input fragment
        bf16x4 Bhh, Bhl;
        #pragma unroll
        for (int r = 0; r < 4; ++r) {
            const unsigned u = __float_as_uint(hv[r]);
            Bhh[r] = (short)(u >> 16);
            const float lo = hv[r] - __uint_as_float(u & 0xFFFF0000u);
            Bhl[r] = (short)(__float_as_uint(lo) >> 16);
        }

        float c[4] = {0.f, 0.f, 0.f, 0.f};

        for (int l = 0; l < 8; ++l) {
            const int rbase = l * 64;
            f32x4 acc[4];
            bf16x4 Ah[4], Al[4];
            #pragma unroll
            for (int t = 0; t < 4; ++t) {
                const int off = (rbase + t * 16 + bcol) * 16 + hi * 4;
                Ah[t] = *(const bf16x4*)(sWh + off);
                Al[t] = *(const bf16x4*)(sWl + off);
                acc[t] = *(const f32x4*)(sB + rbase + t * 16 + hi * 4);
            }
            #pragma unroll
            for (int t = 0; t < 4; ++t) {
                acc[t] = mfma16(Ah[t], Bhh, acc[t]);
                acc[t] = mfma16(Ah[t], Bhl, acc[t]);
                acc[t] = mfma16(Al[t], Bhh, acc[t]);
            }
            // ---- nonlinearity: lane owns units 4hi+r, batch bcol ----
            #pragma unroll
            for (int r = 0; r < 4; ++r) {
                const float yi = acc[0][r];  // -log2e * i
                const float yf = acc[1][r];  // -log2e * f
                const float yg = acc[2][r];  // 2log2e * g
                const float yo = acc[3][r];  // -log2e * o
                const float Di = 1.f + __builtin_amdgcn_exp2f(yi);
                const float Df = 1.f + __builtin_amdgcn_exp2f(yf);
                const float Eg = __builtin_amdgcn_exp2f(yg);
                // c' = c/Df + (Eg-1)/(Di*(Eg+1))  -> single rcp
                const float P = Di * (Eg + 1.f);
                const float num = fmaf(Eg - 1.f, Df, c[r] * P);
                const float cr = num * __builtin_amdgcn_rcpf(Df * P);
                c[r] = cr;
                // h = sig(o)*tanh(c') = (Ec-1)/(Do*(Ec+1)) -> single rcp
                const float Do = 1.f + __builtin_amdgcn_exp2f(yo);
                const float Ec = __builtin_amdgcn_exp2f(cr * G2LOG2E);
                hv[r] = (Ec - 1.f) * __builtin_amdgcn_rcpf(Do * (Ec + 1.f));
            }
            // re-split h for next layer's B fragment (lane-local!)
            #pragma unroll
            for (int r = 0; r < 4; ++r) {
                const unsigned u = __float_as_uint(hv[r]);
                Bhh[r] = (short)(u >> 16);
                const float lo = hv[r] - __uint_as_float(u & 0xFFFF0000u);
                Bhl[r] = (short)(__float_as_uint(lo) >> 16);
            }
        }

        // ---- FC head: out[b] = fc_w . h + fc_b, reduce across 4 hi-lanes ----
        const f32x4 fw = *(const f32x4*)(sFC + hi * 4);
        float p = hv[0] * fw[0] + hv[1] * fw[1] + hv[2] * fw[2] + hv[3] * fw[3];
        p += __shfl_xor(p, 16, 64);
        p += __shfl_xor(p, 32, 64);
        if (hi == 0 && batch < nB) out[batch] = p + sFC[16];
    }
}

extern "C" void kernel_launch(void* const* d_in, const int* in_sizes, int n_in,
                              void* d_out, int out_size, void* d_ws, size_t ws_size,
                              hipStream_t stream) {
    const float* x     = (const float*)d_in[0];
    const float* W_ih0 = (const float*)d_in[1];
    const float* W_ih  = (const float*)d_in[2];
    const float* W_hh  = (const float*)d_in[3];
    const float* b_ih  = (const float*)d_in[4];
    const float* b_hh  = (const float*)d_in[5];
    const float* fc_w  = (const float*)d_in[6];
    const float* fc_b  = (const float*)d_in[7];
    float* out = (float*)d_out;

    const int B = in_sizes[0] / 14;
    lstm_mfma_kernel<<<NBLOCKS, THREADS, 0, stream>>>(
        x, W_ih0, W_ih, W_hh, b_ih, b_hh, fc_w, fc_b, out, B);
}